// Round 1
// baseline (1895.211 us; speedup 1.0000x reference)
//
#include <hip/hip_runtime.h>
#include <stdint.h>

#define INFV 1e9f

// ---------------- ws layout (bytes) ----------------
// sim  : 0          .. 33554432   (1024x8192 f32)
// A    : 33554432   .. +16777216  (1024x8192 u16 prefix-argmin table)
// invt : 50331648   (1024 f32)
// inve : 50335744   (8192 f32)
// h1   : 50368512   (4096 u32)
// h2   : 50384896   (4096 u32)
// h3   : 50401280   (256 u32)
// sel  : 50402304   (16 u32): [0]=rank R, [1]=key prefix, [2]=dropline f32 bits
#define SIM_OFF  0
#define A_OFF    33554432
#define INVT_OFF 50331648
#define INVE_OFF 50335744
#define H1_OFF   50368512
#define H2_OFF   50384896
#define H3_OFF   50401280
#define SEL_OFF  50402304

// ---------------- norms + arange ----------------
__global__ __launch_bounds__(256) void normk(const float* __restrict__ T, const float* __restrict__ E,
                                             float* __restrict__ invt, float* __restrict__ inve,
                                             float* __restrict__ out) {
  int row = blockIdx.x;
  const float* src = (row < 1024) ? (T + (size_t)row * 1024) : (E + (size_t)(row - 1024) * 1024);
  int tid = threadIdx.x;
  float4 v = ((const float4*)src)[tid];
  float s = v.x * v.x + v.y * v.y + v.z * v.z + v.w * v.w;
  #pragma unroll
  for (int d = 1; d < 64; d <<= 1) s += __shfl_xor(s, d);
  __shared__ float wsum[4];
  if ((tid & 63) == 0) wsum[tid >> 6] = s;
  __syncthreads();
  if (tid == 0) {
    float tot = wsum[0] + wsum[1] + wsum[2] + wsum[3];
    float inv = 1.0f / fmaxf(sqrtf(tot), 1e-12f);
    if (row < 1024) invt[row] = inv; else inve[row - 1024] = inv;
  }
  if (blockIdx.x < 4) {
    int i = blockIdx.x * 256 + tid;
    out[1024 + i] = (float)i;
  }
}

// ---------------- f32 GEMM: sim = (T . E^T) * invt * inve ----------------
#define AP 132
__global__ __launch_bounds__(256) void gemmk(const float* __restrict__ T, const float* __restrict__ E,
                                             const float* __restrict__ invt, const float* __restrict__ inve,
                                             float* __restrict__ sim) {
  __shared__ float As[16 * AP];
  __shared__ float Bs[16 * AP];
  int tid = threadIdx.x;
  int i0 = blockIdx.y * 128;   // text rows
  int j0 = blockIdx.x * 128;   // event rows
  int tx = tid & 15, ty = tid >> 4;
  float acc[8][8];
  #pragma unroll
  for (int a = 0; a < 8; a++)
    #pragma unroll
    for (int b = 0; b < 8; b++) acc[a][b] = 0.f;

  int q = tid * 2;
  int r = q >> 2;          // tile row (0..127)
  int s4 = (q & 3) * 4;    // k sub-offset: 0 or 8
  const float* Ag = T + (size_t)(i0 + r) * 1024 + s4;
  const float* Bg = E + (size_t)(j0 + r) * 1024 + s4;

  for (int kb = 0; kb < 64; kb++) {
    float4 a0 = *(const float4*)(Ag + kb * 16);
    float4 a1 = *(const float4*)(Ag + kb * 16 + 4);
    float4 b0 = *(const float4*)(Bg + kb * 16);
    float4 b1 = *(const float4*)(Bg + kb * 16 + 4);
    __syncthreads();
    As[(s4 + 0) * AP + r] = a0.x; As[(s4 + 1) * AP + r] = a0.y;
    As[(s4 + 2) * AP + r] = a0.z; As[(s4 + 3) * AP + r] = a0.w;
    As[(s4 + 4) * AP + r] = a1.x; As[(s4 + 5) * AP + r] = a1.y;
    As[(s4 + 6) * AP + r] = a1.z; As[(s4 + 7) * AP + r] = a1.w;
    Bs[(s4 + 0) * AP + r] = b0.x; Bs[(s4 + 1) * AP + r] = b0.y;
    Bs[(s4 + 2) * AP + r] = b0.z; Bs[(s4 + 3) * AP + r] = b0.w;
    Bs[(s4 + 4) * AP + r] = b1.x; Bs[(s4 + 5) * AP + r] = b1.y;
    Bs[(s4 + 6) * AP + r] = b1.z; Bs[(s4 + 7) * AP + r] = b1.w;
    __syncthreads();
    #pragma unroll
    for (int k = 0; k < 16; k++) {
      float a[8], b[8];
      *(float4*)&a[0] = *(float4*)&As[k * AP + ty * 8];
      *(float4*)&a[4] = *(float4*)&As[k * AP + ty * 8 + 4];
      *(float4*)&b[0] = *(float4*)&Bs[k * AP + tx * 8];
      *(float4*)&b[4] = *(float4*)&Bs[k * AP + tx * 8 + 4];
      #pragma unroll
      for (int ii = 0; ii < 8; ii++)
        #pragma unroll
        for (int jj = 0; jj < 8; jj++) acc[ii][jj] += a[ii] * b[jj];
    }
  }
  float ie[8];
  #pragma unroll
  for (int jj = 0; jj < 8; jj++) ie[jj] = inve[j0 + tx * 8 + jj];
  #pragma unroll
  for (int ii = 0; ii < 8; ii++) {
    float itv = invt[i0 + ty * 8 + ii];
    float o[8];
    #pragma unroll
    for (int jj = 0; jj < 8; jj++) o[jj] = acc[ii][jj] * itv * ie[jj];
    float* dst = &sim[(size_t)(i0 + ty * 8 + ii) * 8192 + j0 + tx * 8];
    *(float4*)dst = *(float4*)&o[0];
    *(float4*)(dst + 4) = *(float4*)&o[4];
  }
}

// ---------------- exact k-th largest: 3-pass radix select ----------------
__device__ inline unsigned keyOf(float f) {
  unsigned u = __float_as_uint(f);
  return (u & 0x80000000u) ? ~u : (u | 0x80000000u);
}

__global__ __launch_bounds__(256) void histk(const float* __restrict__ sim, unsigned* __restrict__ hist,
                                             const unsigned* __restrict__ sel, int pass) {
  __shared__ unsigned lh[4096];
  int tid = threadIdx.x;
  int nb = (pass == 2) ? 256 : 4096;
  for (int b = tid; b < nb; b += 256) lh[b] = 0;
  __syncthreads();
  unsigned prefix = (pass == 0) ? 0u : sel[1];
  size_t base = (size_t)blockIdx.x * 4096 + tid;
  #pragma unroll
  for (int it = 0; it < 16; it++) {
    unsigned u = keyOf(sim[base + it * 256]);
    if (pass == 0) {
      atomicAdd(&lh[u >> 20], 1u);
    } else if (pass == 1) {
      if ((u >> 20) == (prefix >> 20)) atomicAdd(&lh[(u >> 8) & 0xFFFu], 1u);
    } else {
      if ((u >> 8) == (prefix >> 8)) atomicAdd(&lh[u & 0xFFu], 1u);
    }
  }
  __syncthreads();
  for (int b = tid; b < nb; b += 256) if (lh[b]) atomicAdd(&hist[b], lh[b]);
}

__global__ __launch_bounds__(256) void scank(const unsigned* __restrict__ hist, unsigned* __restrict__ sel, int pass) {
  int tid = threadIdx.x;
  int nb = (pass == 2) ? 256 : 4096;
  int per = nb / 256;
  unsigned R = (pass == 0) ? 5872027u : sel[0];      // 1-based ascending rank of k-th largest
  unsigned prefix = (pass == 0) ? 0u : sel[1];
  unsigned cnt[16];
  unsigned s = 0;
  for (int i = 0; i < per; i++) { cnt[i] = hist[tid * per + i]; s += cnt[i]; }
  unsigned incl = s;
  #pragma unroll
  for (int d = 1; d < 64; d <<= 1) { unsigned o = __shfl_up(incl, d); if ((tid & 63) >= d) incl += o; }
  __shared__ unsigned wt[4], wsc[4];
  if ((tid & 63) == 63) wt[tid >> 6] = incl;
  __syncthreads();
  if (tid < 4) {
    unsigned v = wt[tid];
    #pragma unroll
    for (int d = 1; d < 4; d <<= 1) { unsigned o = __shfl_up(v, d); if (tid >= d) v += o; }
    wsc[tid] = v;
  }
  __syncthreads();
  unsigned excl = incl - s + ((tid >> 6) ? wsc[(tid >> 6) - 1] : 0u);
  unsigned c = excl;
  for (int i = 0; i < per; i++) {
    unsigned nc = c + cnt[i];
    if (c < R && R <= nc) {
      unsigned bin = (unsigned)(tid * per + i);
      sel[0] = R - c;
      unsigned np_;
      if (pass == 0) np_ = bin << 20;
      else if (pass == 1) np_ = prefix | (bin << 8);
      else np_ = prefix | bin;
      sel[1] = np_;
      if (pass == 2) {
        unsigned key = np_;
        unsigned u = (key & 0x80000000u) ? (key ^ 0x80000000u) : ~key;
        ((float*)sel)[2] = __uint_as_float(u);
      }
    }
    c = nc;
  }
}

// ---------------- Drop-DTW DP: rowwise prefix-min with latest-tie argmin ----------------
// B_zi[j] = min(D0,D1)[zi][j] = inclusive prefix-min_j of t[j] = B_{zi-1}[j-1] + (drop - sim[zi-1][j-1]).
// A[zi-1][j-1] = latest argmin over prefix -> exactly the match column the reference backtrack picks.
__global__ __launch_bounds__(512) void dpk(const float* __restrict__ sim, const unsigned* __restrict__ sel,
                                           unsigned short* __restrict__ A, float* __restrict__ out) {
  int tid = threadIdx.x;            // 512 threads, 16 cols each
  int lane = tid & 63, w = tid >> 6; // 8 waves
  float drop = ((const float*)sel)[2];
  __shared__ float wtv[8], wsv[8];
  __shared__ int wti[8], wsi[8];
  if (tid < 8) { wsv[tid] = 0.f; wsi[tid] = 0; }
  __syncthreads();

  float r[16];
  #pragma unroll
  for (int u = 0; u < 16; u++) r[u] = 0.f;   // B_0 = 0 everywhere
  float rlast = 0.f;
  int p0 = tid * 16;                          // sim col base; j = p0+1 .. p0+16
  const float* srow = sim + p0;

  float cur[16], nxt[16];
  {
    const float* nr = srow;
    *(float4*)&cur[0]  = *(const float4*)(nr + 0);
    *(float4*)&cur[4]  = *(const float4*)(nr + 4);
    *(float4*)&cur[8]  = *(const float4*)(nr + 8);
    *(float4*)&cur[12] = *(const float4*)(nr + 12);
  }

  for (int zi = 1; zi <= 1024; zi++) {
    if (zi < 1024) {
      const float* nr = srow + (size_t)zi * 8192;
      *(float4*)&nxt[0]  = *(const float4*)(nr + 0);
      *(float4*)&nxt[4]  = *(const float4*)(nr + 4);
      *(float4*)&nxt[8]  = *(const float4*)(nr + 8);
      *(float4*)&nxt[12] = *(const float4*)(nr + 12);
    }
    // B_prev[p0] handoff: previous thread's last B, or wave boundary from LDS
    float up = __shfl_up(rlast, 1);
    float pb0;
    if (lane == 0) {
      if (w == 0) pb0 = (zi == 1) ? 0.f : INFV;  // B_prev[0]: row0 -> 0, else INF
      else pb0 = wsv[w - 1];
    } else pb0 = up;

    // pass A: thread-local (min, latest-argmin) total
    float mv; int mi;
    #pragma unroll
    for (int u = 0; u < 16; u++) {
      float pb = (u == 0) ? pb0 : r[u - 1];
      float tv = pb + (drop - cur[u]);
      if (u == 0) { mv = tv; mi = p0 + 1; }
      else if (tv <= mv) { mv = tv; mi = p0 + 1 + u; }
    }
    // wave inclusive scan (later lane wins ties)
    float v = mv; int ix = mi;
    #pragma unroll
    for (int d = 1; d < 64; d <<= 1) {
      float ov = __shfl_up(v, d); int oi = __shfl_up(ix, d);
      if (lane >= d) { if (!(v <= ov)) { v = ov; ix = oi; } }
    }
    if (lane == 63) { wtv[w] = v; wti[w] = ix; }
    __syncthreads();
    if (w == 0 && lane < 8) {
      float vv = wtv[lane]; int vi = wti[lane];
      #pragma unroll
      for (int d = 1; d < 8; d <<= 1) {
        float ov = __shfl_up(vv, d); int oi = __shfl_up(vi, d);
        if (lane >= d) { if (!(vv <= ov)) { vv = ov; vi = oi; } }
      }
      wsv[lane] = vv; wsi[lane] = vi;
    }
    __syncthreads();
    float bev; int bei;
    if (w == 0) { bev = INFV; bei = 0; } else { bev = wsv[w - 1]; bei = wsi[w - 1]; }
    float wev = __shfl_up(v, 1); int wei = __shfl_up(ix, 1);
    if (lane == 0) { wev = INFV; wei = 0; }
    float pv; int pi;
    if (wev <= bev) { pv = wev; pi = wei; } else { pv = bev; pi = bei; }

    // pass B: final inclusive values + argmin per element
    int aout[16];
    float prev_r;
    #pragma unroll
    for (int u = 0; u < 16; u++) {
      float pb = (u == 0) ? pb0 : prev_r;
      prev_r = r[u];
      float tv = pb + (drop - cur[u]);
      if (tv <= pv) { pv = tv; pi = p0 + 1 + u; }
      r[u] = pv;
      aout[u] = pi;
    }
    rlast = r[15];
    unsigned pk[8];
    #pragma unroll
    for (int c = 0; c < 8; c++) pk[c] = (unsigned)(aout[2 * c] & 0xFFFF) | ((unsigned)(aout[2 * c + 1] & 0xFFFF) << 16);
    uint4* dst = (uint4*)(A + (size_t)(zi - 1) * 8192 + p0);
    dst[0] = make_uint4(pk[0], pk[1], pk[2], pk[3]);
    dst[1] = make_uint4(pk[4], pk[5], pk[6], pk[7]);

    #pragma unroll
    for (int u = 0; u < 16; u++) cur[u] = nxt[u];
  }
  if (tid == 511) out[2048] = r[15];  // min(D0f[K,N], D1f[K,N])
}

// ---------------- backtrack ----------------
__global__ void btk(const unsigned short* __restrict__ A, float* __restrict__ out) {
  if (threadIdx.x != 0) return;
  int j = 8192;
  for (int zi = 1024; zi >= 1; zi--) {
    int p = A[(size_t)(zi - 1) * 8192 + (j - 1)];  // latest prefix-argmin <= j
    out[zi - 1] = (float)(p - 1);
    j = p - 1;
  }
}

extern "C" void kernel_launch(void* const* d_in, const int* in_sizes, int n_in,
                              void* d_out, int out_size, void* d_ws, size_t ws_size,
                              hipStream_t stream) {
  (void)in_sizes; (void)n_in; (void)out_size; (void)ws_size;
  const float* T = (const float*)d_in[0];
  const float* E = (const float*)d_in[1];
  char* ws = (char*)d_ws;
  float* sim = (float*)(ws + SIM_OFF);
  unsigned short* A = (unsigned short*)(ws + A_OFF);
  float* invt = (float*)(ws + INVT_OFF);
  float* inve = (float*)(ws + INVE_OFF);
  unsigned* h1 = (unsigned*)(ws + H1_OFF);
  unsigned* h2 = (unsigned*)(ws + H2_OFF);
  unsigned* h3 = (unsigned*)(ws + H3_OFF);
  unsigned* sel = (unsigned*)(ws + SEL_OFF);
  float* out = (float*)d_out;

  hipMemsetAsync(ws + H1_OFF, 0, 16384 + 16384 + 1024 + 64, stream);
  normk<<<9216, 256, 0, stream>>>(T, E, invt, inve, out);
  gemmk<<<dim3(64, 8), 256, 0, stream>>>(T, E, invt, inve, sim);
  histk<<<2048, 256, 0, stream>>>(sim, h1, sel, 0);
  scank<<<1, 256, 0, stream>>>(h1, sel, 0);
  histk<<<2048, 256, 0, stream>>>(sim, h2, sel, 1);
  scank<<<1, 256, 0, stream>>>(h2, sel, 1);
  histk<<<2048, 256, 0, stream>>>(sim, h3, sel, 2);
  scank<<<1, 256, 0, stream>>>(h3, sel, 2);
  dpk<<<1, 512, 0, stream>>>(sim, sel, A, out);
  btk<<<1, 64, 0, stream>>>(A, out);
}